// Round 8
// baseline (18634.126 us; speedup 1.0000x reference)
//
#include <hip/hip_runtime.h>
#include <cstdint>
#include <cstddef>

// ---------------------------------------------------------------------------
// 2-layer LSTM sampler, BATCH=2048, 100 steps, exact jax.random.categorical
// reproduction (threefry2x32, partitionable bits). Round-8: A-operand moved
// from LDS staging to a register ping-pong of direct packed global loads
// (each lane's fragment is a contiguous 16B in the packed layout). LDS now
// stages only W (shared by 4 waves). Cuts LDS bytes/iter ~3x: was 128 reads
// + 48KB gl_lds writes, now 64 reads + 16KB writes. Numerics identical to
// rounds 2-7 (absmax 0.0 proven): fp16x3 split MFMA + fast-fp64 epilogue.
// ---------------------------------------------------------------------------

constexpr int PAD_TOK = 0, BOS_TOK = 1, EOS_TOK = 2;
constexpr int VOCAB = 32, EMB = 64, HID = 1024, BATCH = 2048, MAXLEN = 100;
constexpr int BK = 32;               // k-tile depth (halfwords)
constexpr int NKT_H = HID / BK;      // 32 k-tiles for K=1024
constexpr float SCALE = 64.0f;       // fp16-split scale (keeps lo normal)
constexpr double INV_S2 = 1.0 / 4096.0;

using half8 = __attribute__((ext_vector_type(8))) _Float16;
using f32x4 = __attribute__((ext_vector_type(4))) float;
typedef unsigned short u16;
typedef uint32_t u32;

__device__ __forceinline__ u32 rotl32(u32 v, int d) {
  return (v << d) | (v >> (32 - d));
}

__device__ __forceinline__ void threefry2x32(u32 k0, u32 k1, u32 x0, u32 x1,
                                             u32& y0, u32& y1) {
  const u32 k2 = k0 ^ k1 ^ 0x1BD11BDAu;
#define TF_ROUND(r) do { x0 += x1; x1 = rotl32(x1, (r)); x1 ^= x0; } while (0)
  x0 += k0; x1 += k1;
  TF_ROUND(13); TF_ROUND(15); TF_ROUND(26); TF_ROUND(6);
  x0 += k1; x1 += k2 + 1u;
  TF_ROUND(17); TF_ROUND(29); TF_ROUND(16); TF_ROUND(24);
  x0 += k2; x1 += k0 + 2u;
  TF_ROUND(13); TF_ROUND(15); TF_ROUND(26); TF_ROUND(6);
  x0 += k0; x1 += k1 + 3u;
  TF_ROUND(17); TF_ROUND(29); TF_ROUND(16); TF_ROUND(24);
  x0 += k1; x1 += k2 + 4u;
  TF_ROUND(13); TF_ROUND(15); TF_ROUND(26); TF_ROUND(6);
  x0 += k2; x1 += k0 + 5u;
#undef TF_ROUND
  y0 = x0; y1 = x1;
}

// async global->LDS, 16 bytes per lane; LDS dest = wave-uniform base + lane*16
__device__ __forceinline__ void gl_lds16(const void* g, void* l) {
  __builtin_amdgcn_global_load_lds(
      (const __attribute__((address_space(1))) void*)g,
      (__attribute__((address_space(3))) void*)l, 16, 0, 0);
}

// ---- fast fp64 transcendentals (rel err ~1e-11, way below f32 ulp) --------
__device__ __forceinline__ double rcp1p(double q) {  // 1/(1+q), q >= 0
  const double d = 1.0 + q;
  double r = (double)__builtin_amdgcn_rcpf((float)d);
  r = r * fma(-d, r, 2.0);
  r = r * fma(-d, r, 2.0);
  return r;
}
__device__ __forceinline__ double exp2d(double t) {  // 2^t, |t| < ~120
  const double n = rint(t);
  const double f = t - n;  // |f| <= 0.5
  double p = 1.0178086009239699e-07;   // ln2^9/9!
  p = fma(p, f, 1.3215542443841225e-06);
  p = fma(p, f, 1.5252733804059840e-05);
  p = fma(p, f, 1.5403530393381610e-04);
  p = fma(p, f, 1.3333558146428443e-03);
  p = fma(p, f, 9.6181291076284772e-03);
  p = fma(p, f, 5.5504108664821580e-02);
  p = fma(p, f, 2.4022650695910071e-01);
  p = fma(p, f, 6.9314718055994531e-01);
  p = fma(p, f, 1.0);
  const long long e = ((long long)(int)n + 1023) << 52;
  return p * __longlong_as_double(e);
}
__device__ __forceinline__ double sigd(double x) {   // 1/(1+e^-x)
  return rcp1p(exp2d(x * -1.4426950408889634));
}
__device__ __forceinline__ double tanhd(double x) {  // 2*sig(2x)-1
  return fma(2.0, rcp1p(exp2d(x * -2.8853900817779268)), -1.0);
}

// ---------------------------------------------------------------------------
// Fused fp16 split + fragment-order pack for one weight matrix [4H x K].
// chunk[(ut*nkt + kt)*512 + slot], slot = fm*64 + kg*16 + r15; element e:
//   W[gate*HID + ut*32 + ugrp*16 + r15][kt*32 + kg*8 + e],
//   gate = fm&3, ugrp = fm>>2   (GATE-INTERLEAVED: tile ni <-> gate).
// ---------------------------------------------------------------------------
__global__ __launch_bounds__(256) void pack_w(
    const float* __restrict__ src, int K, int nkt,
    uint4* __restrict__ dhi, uint4* __restrict__ dlo, int nchunks) {
  const int g = blockIdx.x * 256 + threadIdx.x;
  if (g >= nchunks) return;
  const int ut = g / (nkt * 512);
  const int rem = g - ut * (nkt * 512);
  const int kt = rem >> 9;
  const int slot = rem & 511;
  const int fm = slot >> 6, kg = (slot >> 4) & 3, r15 = slot & 15;
  const int row = (fm & 3) * HID + ut * 32 + (fm >> 2) * 16 + r15;
  const int col = kt * 32 + kg * 8;
  const float* s = src + (size_t)row * K + col;
  u16 hh[8], ll[8];
#pragma unroll
  for (int e = 0; e < 8; ++e) {
    const float x = s[e] * SCALE;
    const _Float16 h = (_Float16)x;
    const float rm = x - (float)h;
    const _Float16 l = (_Float16)rm;
    hh[e] = __builtin_bit_cast(u16, h);
    ll[e] = __builtin_bit_cast(u16, l);
  }
  dhi[g] = make_uint4((u32)hh[0] | ((u32)hh[1] << 16),
                      (u32)hh[2] | ((u32)hh[3] << 16),
                      (u32)hh[4] | ((u32)hh[5] << 16),
                      (u32)hh[6] | ((u32)hh[7] << 16));
  dlo[g] = make_uint4((u32)ll[0] | ((u32)ll[1] << 16),
                      (u32)ll[2] | ((u32)ll[3] << 16),
                      (u32)ll[4] | ((u32)ll[5] << 16),
                      (u32)ll[6] | ((u32)ll[7] << 16));
}

// ---------------------------------------------------------------------------
__global__ __launch_bounds__(256) void split_kernel(
    const float* __restrict__ src, u16* __restrict__ hi, u16* __restrict__ lo,
    int n) {
  const int i = blockIdx.x * 256 + threadIdx.x;
  if (i >= n) return;
  const float x = src[i] * SCALE;
  const _Float16 h = (_Float16)x;
  const float rem = x - (float)h;
  const _Float16 l = (_Float16)rem;
  hi[i] = __builtin_bit_cast(u16, h);
  lo[i] = __builtin_bit_cast(u16, l);
}

// ---------------------------------------------------------------------------
__global__ __launch_bounds__(256) void init_kernel(
    const int* __restrict__ prevs, float* __restrict__ c0,
    float* __restrict__ c1, u16* __restrict__ h0hi0, u16* __restrict__ h0lo0,
    u16* __restrict__ h0hi1, u16* __restrict__ h0lo1,
    u16* __restrict__ h1hi0, u16* __restrict__ h1lo0,
    u16* __restrict__ h1hi1, u16* __restrict__ h1lo1,
    int* __restrict__ prev, int* __restrict__ is_end,
    int* __restrict__ lengths, u32* __restrict__ keys,
    int* __restrict__ out_tok) {
  const int tid = blockIdx.x * 256 + threadIdx.x;
  const int total = BATCH * HID;
  if (tid < total) {
    c0[tid] = 0.0f; c1[tid] = 0.0f;
    h0hi0[tid] = 0; h0lo0[tid] = 0; h0hi1[tid] = 0; h0lo1[tid] = 0;
    h1hi0[tid] = 0; h1lo0[tid] = 0; h1hi1[tid] = 0; h1lo1[tid] = 0;
  }
  if (tid < BATCH) {
    const int p = prevs[tid];
    prev[tid] = p;
    is_end[tid] = (p == EOS_TOK) ? 1 : 0;
    lengths[tid] = 0;
    out_tok[(size_t)tid * (MAXLEN + 1)] = p;
  }
  if (tid < MAXLEN) {
    u32 y0, y1;
    threefry2x32(0u, 42u, 0u, (u32)tid, y0, y1);
    keys[2 * tid] = y0;
    keys[2 * tid + 1] = y1;
  }
}

// ---------------------------------------------------------------------------
// MFMA LSTM layer. 256 blocks (8 mt x 32 ut), 512 threads = 8 waves (4wm x
// 2wn), each wave 64x64 output. gates = A0*W0^T + A1*W1^T (fp16x3), fused
// fast-fp64 in-register cell update (gate-interleaved acc).
// A operand: direct coalesced global_load_dwordx4 into MFMA VGPRs, register
// ping-pong (Ah0/Ah1 named sets, static indices). W operand: gl_lds16 into
// 2x16KB LDS buffers (shared by 4 waves). One barrier per k-tile.
// ---------------------------------------------------------------------------
template <bool GATHER, bool WRITE_F32>
__global__ __launch_bounds__(512, 2) void lstm_mfma(
    const uint4* __restrict__ A0p_hi, const uint4* __restrict__ A0p_lo,
    const u16* __restrict__ Ehi, const u16* __restrict__ Elo,
    const int* __restrict__ ptok, int nk0,
    const uint4* __restrict__ A1p_hi, const uint4* __restrict__ A1p_lo,
    const uint4* __restrict__ W0hi, const uint4* __restrict__ W0lo,
    const uint4* __restrict__ W1hi, const uint4* __restrict__ W1lo,
    const float* __restrict__ bih, const float* __restrict__ bhh,
    float* __restrict__ Cst, float* __restrict__ Hf32,
    uint4* __restrict__ Hp_hi, uint4* __restrict__ Hp_lo) {
  __shared__ uint4 lds4[2560];  // 40960 B: 2 x 16KB W bufs; h-pack overlay
  char* lds = (char*)lds4;

  const int tid = threadIdx.x;          // 0..511
  const int lane = tid & 63;
  const int wid = tid >> 6;             // 0..7
  const int wm = wid >> 1, wn = wid & 1;

  const int bid = blockIdx.x;           // 256 blocks
  const int swz = (bid & 7) * 32 + (bid >> 3);
  const int ut = swz >> 3;              // 0..31
  const int mt = swz & 7;               // 0..7
  const int u0 = ut * 32;
  const int row0 = mt * 256;

  const int r15 = lane & 15;
  const int kgrp = lane >> 4;           // 0..3

  // emb-gather tokens: one per A fragment row this lane owns (mi = 0..3)
  int tok4[4];
  if (GATHER) {
#pragma unroll
    for (int mi = 0; mi < 4; ++mi)
      tok4[mi] = ptok[row0 + (wm * 4 + mi) * 16 + r15];
  }

  const int NT = nk0 + NKT_H;           // 34 (layer0) or 64 (layer1): even

  auto ldsW = [&](int buf, int pl, int slot) -> char* {
    return lds + buf * 16384 + pl * 8192 + slot * 16;
  };

  auto stageW = [&](int buf, int kt) {
    const bool s0 = kt < nk0;
    const int ktl = s0 ? kt : kt - nk0;
    const uint4* wh = s0 ? W0hi : W1hi;
    const uint4* wl = s0 ? W0lo : W1lo;
    const int wbase = (ut * (s0 ? nk0 : NKT_H) + ktl) * 512 + wid * 64;
    gl_lds16(wh + wbase + lane, ldsW(buf, 0, wid * 64));
    gl_lds16(wl + wbase + lane, ldsW(buf, 1, wid * 64));
  };

  // A fragment loads: lane's 16B frag = packed[(mt*NKT_H+ktl)*1024 +
  // (wm*4+mi)*64 + lane]  (coalesced dwordx4). GATHER phase: per-lane emb row.
  auto loadA = [&](int kt, uint4* Ah, uint4* Al) {
    const bool s0 = kt < nk0;
    const int ktl = s0 ? kt : kt - nk0;
    if (GATHER && s0) {
#pragma unroll
      for (int mi = 0; mi < 4; ++mi) {
        const size_t ao = (size_t)tok4[mi] * EMB + ktl * 32 + kgrp * 8;
        Ah[mi] = *(const uint4*)(Ehi + ao);
        Al[mi] = *(const uint4*)(Elo + ao);
      }
    } else {
      const uint4* ah_ = s0 ? A0p_hi : A1p_hi;
      const uint4* al_ = s0 ? A0p_lo : A1p_lo;
      const int ab = (mt * NKT_H + ktl) * 1024 + wm * 256 + lane;
#pragma unroll
      for (int mi = 0; mi < 4; ++mi) {
        Ah[mi] = ah_[ab + mi * 64];
        Al[mi] = al_[ab + mi * 64];
      }
    }
  };

  f32x4 acc[4][4] = {};  // acc[mi][gate]

  auto compute = [&](const uint4* AhF, const uint4* AlF, int buf) {
    half8 ah[4], al[4];
#pragma unroll
    for (int mi = 0; mi < 4; ++mi) {
      ah[mi] = __builtin_bit_cast(half8, AhF[mi]);
      al[mi] = __builtin_bit_cast(half8, AlF[mi]);
    }
#pragma unroll
    for (int ni = 0; ni < 4; ++ni) {
      const half8 bh = *(const half8*)ldsW(buf, 0, (wn * 4 + ni) * 64 + lane);
      const half8 bl = *(const half8*)ldsW(buf, 1, (wn * 4 + ni) * 64 + lane);
#pragma unroll
      for (int mi = 0; mi < 4; ++mi) {
        acc[mi][ni] =
            __builtin_amdgcn_mfma_f32_16x16x32_f16(ah[mi], bh, acc[mi][ni], 0, 0, 0);
        acc[mi][ni] =
            __builtin_amdgcn_mfma_f32_16x16x32_f16(ah[mi], bl, acc[mi][ni], 0, 0, 0);
        acc[mi][ni] =
            __builtin_amdgcn_mfma_f32_16x16x32_f16(al[mi], bh, acc[mi][ni], 0, 0, 0);
      }
    }
  };

  uint4 Ah0[4], Al0[4], Ah1[4], Al1[4];
  loadA(0, Ah0, Al0);
  stageW(0, 0);
  __syncthreads();  // W buf0 ready (drains vmcnt); A0 regs guarded by dep
#pragma unroll 1
  for (int t = 0; t < NT; t += 2) {
    // t+1 always < NT (NT even)
    loadA(t + 1, Ah1, Al1);
    stageW(1, t + 1);
    compute(Ah0, Al0, 0);
    __syncthreads();  // buf1 + A1 landed during compute; buf0 free
    if (t + 2 < NT) {
      loadA(t + 2, Ah0, Al0);
      stageW(0, t + 2);
    }
    compute(Ah1, Al1, 1);
    __syncthreads();
  }

  // ---- epilogue: in-register fast-fp64 cell update -------------------------
  const int u_loc = wn * 16 + r15;      // 0..31
  const int u = u0 + u_loc;
  double bsum[4];
#pragma unroll
  for (int g = 0; g < 4; ++g)
    bsum[g] = (double)bih[g * HID + u] + (double)bhh[g * HID + u];

  float* Cb = Cst + (size_t)(mt * 32 + ut) * 8192;  // [256 rows][32 units]
  u16* hhT = (u16*)lds;                 // [256][40] u16 (20KB)
  u16* hlT = (u16*)(lds + 20480);       // [256][40] u16
  const int hi4 = lane >> 4;

#pragma unroll
  for (int mi = 0; mi < 4; ++mi) {
#pragma unroll
    for (int r = 0; r < 4; ++r) {
      const int row = wm * 64 + mi * 16 + hi4 * 4 + r;
      const double gI = (double)acc[mi][0][r] * INV_S2 + bsum[0];
      const double gF = (double)acc[mi][1][r] * INV_S2 + bsum[1];
      const double gG = (double)acc[mi][2][r] * INV_S2 + bsum[2];
      const double gO = (double)acc[mi][3][r] * INV_S2 + bsum[3];
      const double ii = sigd(gI);
      const double ff = sigd(gF);
      const double gt = tanhd(gG);
      const double oo = sigd(gO);
      const int co = row * 32 + u_loc;
      const double cn = ff * (double)Cb[co] + ii * gt;
      Cb[co] = (float)cn;
      const float hf = (float)(oo * tanhd(cn));
      if (WRITE_F32) Hf32[(size_t)(row0 + row) * HID + u] = hf;
      const float hs = hf * SCALE;
      const _Float16 hh = (_Float16)hs;
      const float rm = hs - (float)hh;
      const _Float16 hl = (_Float16)rm;
      hhT[row * 40 + u_loc] = __builtin_bit_cast(u16, hh);
      hlT[row * 40 + u_loc] = __builtin_bit_cast(u16, hl);
    }
  }
  __syncthreads();

  // pack h hi/lo planes: 1024 chunks, 2 per thread, coalesced global stores
  const size_t mtut = ((size_t)mt * NKT_H + ut) * 1024;
#pragma unroll
  for (int j = 0; j < 2; ++j) {
    const int g = tid + j * 512;
    const int fA = g >> 6, kg = (g >> 4) & 3, rr = g & 15;
    const int row = fA * 16 + rr;
    const uint4 vh = *(const uint4*)(hhT + row * 40 + kg * 8);
    const uint4 vl = *(const uint4*)(hlT + row * 40 + kg * 8);
    Hp_hi[mtut + g] = vh;
    Hp_lo[mtut + g] = vl;
  }
}

// ---------------------------------------------------------------------------
// Logits + gumbel + argmax + EOS bookkeeping (fp64, proven exact).
// ---------------------------------------------------------------------------
__global__ __launch_bounds__(256) void sample_kernel(
    const float* __restrict__ h1, const float* __restrict__ Wout,
    const float* __restrict__ bout, const u32* __restrict__ keys, int t,
    int* __restrict__ prev, int* __restrict__ is_end, int* __restrict__ lengths,
    int* __restrict__ out_tok, int* __restrict__ len_out) {
  const int wave = threadIdx.x >> 6;
  const int lane = threadIdx.x & 63;
  const int row = blockIdx.x * 4 + wave;
  const int v = lane & 31;
  const int half = lane >> 5;

  const float* hseg = h1 + (size_t)row * HID + half * (HID / 2);
  const float* wseg = Wout + (size_t)v * HID + half * (HID / 2);

  double acc = 0.0;
#pragma unroll 4
  for (int k = 0; k < HID / 2; k += 4) {
    const float4 w = *(const float4*)(wseg + k);
    const float4 h = *(const float4*)(hseg + k);
    acc = fma((double)w.x, (double)h.x, acc);
    acc = fma((double)w.y, (double)h.y, acc);
    acc = fma((double)w.z, (double)h.z, acc);
    acc = fma((double)w.w, (double)h.w, acc);
  }
  acc += __shfl_xor(acc, 32);

  const u32 k0 = keys[2 * t], k1 = keys[2 * t + 1];
  u32 y0, y1;
  threefry2x32(k0, k1, 0u, (u32)(row * VOCAB + v), y0, y1);
  const u32 bits = y0 ^ y1;
  const float f = __uint_as_float((bits >> 9) | 0x3f800000u) - 1.0f;
  const float uu = fmaxf(f, 1.17549435e-38f);
  const double g = -log(-log((double)uu));

  double z = acc + (double)bout[v] + g;
  int idx = v;
#pragma unroll
  for (int m = 1; m < 32; m <<= 1) {
    const double zo = __shfl_xor(z, m);
    const int io = __shfl_xor(idx, m);
    if (zo > z || (zo == z && io < idx)) { z = zo; idx = io; }
  }

  if (lane == 0) {
    const int e = is_end[row];
    const int cur = e ? PAD_TOK : idx;
    const int len = lengths[row] + (e ? 0 : 1);
    const int enew = e | (cur == EOS_TOK ? 1 : 0);
    prev[row] = cur;
    is_end[row] = enew;
    lengths[row] = len;
    out_tok[(size_t)row * (MAXLEN + 1) + t + 1] = cur;
    if (len_out) len_out[row] = len + 1;  // reference returns lengths+1 (BOS)
  }
}

// ---------------------------------------------------------------------------
extern "C" void kernel_launch(void* const* d_in, const int* in_sizes, int n_in,
                              void* d_out, int out_size, void* d_ws,
                              size_t ws_size, hipStream_t stream) {
  const int* prevs = (const int*)d_in[0];
  const float* emb = (const float*)d_in[1];
  const float* Wih0 = (const float*)d_in[2];
  const float* Whh0 = (const float*)d_in[3];
  const float* bih0 = (const float*)d_in[4];
  const float* bhh0 = (const float*)d_in[5];
  const float* Wih1 = (const float*)d_in[6];
  const float* Whh1 = (const float*)d_in[7];
  const float* bih1 = (const float*)d_in[8];
  const float* bhh1 = (const float*)d_in[9];
  const float* Wout = (const float*)d_in[10];
  const float* bout = (const float*)d_in[11];

  const size_t SH = (size_t)BATCH * HID;       // 2M elements
  const size_t CH = SH / 8;                    // 262144 uint4 per h plane
  const size_t CW = (size_t)32 * NKT_H * 512;  // 524288 chunks (K=1024)
  const size_t CW0 = (size_t)32 * 2 * 512;     // 32768 chunks (Wih0, K=64)

  float* c0 = (float*)d_ws;                    // block layout [mt*32+ut][256][32]
  float* c1 = c0 + SH;
  float* h1f = c1 + SH;
  uint4* q = (uint4*)(h1f + SH);
  uint4* ph0hi[2] = {q, q + CH};
  uint4* ph0lo[2] = {q + 2 * CH, q + 3 * CH};
  uint4* ph1hi[2] = {q + 4 * CH, q + 5 * CH};
  uint4* ph1lo[2] = {q + 6 * CH, q + 7 * CH};
  uint4* pw = q + 8 * CH;
  uint4* pwih0h = pw;              uint4* pwih0l = pwih0h + CW0;
  uint4* pwhh0h = pwih0l + CW0;    uint4* pwhh0l = pwhh0h + CW;
  uint4* pwih1h = pwhh0l + CW;     uint4* pwih1l = pwih1h + CW;
  uint4* pwhh1h = pwih1l + CW;     uint4* pwhh1l = pwhh1h + CW;
  u16* embh = (u16*)(pwhh1l + CW);
  u16* embl = embh + VOCAB * EMB;
  int* prev = (int*)(embl + VOCAB * EMB);
  int* is_end = prev + BATCH;
  int* lengths = is_end + BATCH;
  u32* keys = (u32*)(lengths + BATCH);
  // total ~105 MB

  int* out_tok = (int*)d_out;
  int* len_out = out_tok + (size_t)BATCH * (MAXLEN + 1);

  init_kernel<<<dim3((BATCH * HID) / 256), 256, 0, stream>>>(
      prevs, c0, c1, (u16*)ph0hi[0], (u16*)ph0lo[0], (u16*)ph0hi[1],
      (u16*)ph0lo[1], (u16*)ph1hi[0], (u16*)ph1lo[0], (u16*)ph1hi[1],
      (u16*)ph1lo[1], prev, is_end, lengths, keys, out_tok);

  split_kernel<<<dim3((VOCAB * EMB + 255) / 256), 256, 0, stream>>>(
      emb, embh, embl, VOCAB * EMB);
  pack_w<<<dim3((int)((CW0 + 255) / 256)), 256, 0, stream>>>(
      Wih0, EMB, 2, pwih0h, pwih0l, (int)CW0);
  pack_w<<<dim3((int)((CW + 255) / 256)), 256, 0, stream>>>(
      Whh0, HID, NKT_H, pwhh0h, pwhh0l, (int)CW);
  pack_w<<<dim3((int)((CW + 255) / 256)), 256, 0, stream>>>(
      Wih1, HID, NKT_H, pwih1h, pwih1l, (int)CW);
  pack_w<<<dim3((int)((CW + 255) / 256)), 256, 0, stream>>>(
      Whh1, HID, NKT_H, pwhh1h, pwhh1l, (int)CW);

  int p = 0;
  for (int t = 0; t < MAXLEN; ++t) {
    lstm_mfma<true, false><<<dim3(256), 512, 0, stream>>>(
        nullptr, nullptr, embh, embl, prev, 2, ph0hi[p], ph0lo[p],
        pwih0h, pwih0l, pwhh0h, pwhh0l, bih0, bhh0, c0, nullptr,
        ph0hi[p ^ 1], ph0lo[p ^ 1]);
    lstm_mfma<false, true><<<dim3(256), 512, 0, stream>>>(
        ph0hi[p ^ 1], ph0lo[p ^ 1], nullptr, nullptr, nullptr, NKT_H,
        ph1hi[p], ph1lo[p], pwih1h, pwih1l, pwhh1h, pwhh1l, bih1, bhh1,
        c1, h1f, ph1hi[p ^ 1], ph1lo[p ^ 1]);
    sample_kernel<<<dim3(BATCH / 4), 256, 0, stream>>>(
        h1f, Wout, bout, keys, t, prev, is_end, lengths, out_tok,
        (t == MAXLEN - 1) ? len_out : nullptr);
    p ^= 1;
  }
  (void)in_sizes; (void)n_in; (void)out_size; (void)ws_size;
}

// Round 9
// 17972.572 us; speedup vs baseline: 1.0368x; 1.0368x over previous
//
#include <hip/hip_runtime.h>
#include <cstdint>
#include <cstddef>

// ---------------------------------------------------------------------------
// 2-layer LSTM sampler, BATCH=2048, 100 steps, exact jax.random.categorical
// reproduction (threefry2x32, partitionable bits). Round-9: round-7 operand
// path (A+W via global_load_lds, proven absmax 0.0) + T3/T4 pipeline:
// 3-deep LDS ring (3 x 48KB) with COUNTED s_waitcnt vmcnt(12/6/0) + raw
// s_barrier -- loads stay in flight across barriers instead of draining to 0
// every k-tile (rounds 3-8 paid ~full L2/L3 latency per iteration).
// ---------------------------------------------------------------------------

constexpr int PAD_TOK = 0, BOS_TOK = 1, EOS_TOK = 2;
constexpr int VOCAB = 32, EMB = 64, HID = 1024, BATCH = 2048, MAXLEN = 100;
constexpr int BK = 32;               // k-tile depth (halfwords)
constexpr int NKT_H = HID / BK;      // 32 k-tiles for K=1024
constexpr float SCALE = 64.0f;       // fp16-split scale (keeps lo normal)
constexpr double INV_S2 = 1.0 / 4096.0;

using half8 = __attribute__((ext_vector_type(8))) _Float16;
using f32x4 = __attribute__((ext_vector_type(4))) float;
typedef unsigned short u16;
typedef uint32_t u32;

__device__ __forceinline__ u32 rotl32(u32 v, int d) {
  return (v << d) | (v >> (32 - d));
}

__device__ __forceinline__ void threefry2x32(u32 k0, u32 k1, u32 x0, u32 x1,
                                             u32& y0, u32& y1) {
  const u32 k2 = k0 ^ k1 ^ 0x1BD11BDAu;
#define TF_ROUND(r) do { x0 += x1; x1 = rotl32(x1, (r)); x1 ^= x0; } while (0)
  x0 += k0; x1 += k1;
  TF_ROUND(13); TF_ROUND(15); TF_ROUND(26); TF_ROUND(6);
  x0 += k1; x1 += k2 + 1u;
  TF_ROUND(17); TF_ROUND(29); TF_ROUND(16); TF_ROUND(24);
  x0 += k2; x1 += k0 + 2u;
  TF_ROUND(13); TF_ROUND(15); TF_ROUND(26); TF_ROUND(6);
  x0 += k0; x1 += k1 + 3u;
  TF_ROUND(17); TF_ROUND(29); TF_ROUND(16); TF_ROUND(24);
  x0 += k1; x1 += k2 + 4u;
  TF_ROUND(13); TF_ROUND(15); TF_ROUND(26); TF_ROUND(6);
  x0 += k2; x1 += k0 + 5u;
#undef TF_ROUND
  y0 = x0; y1 = x1;
}

// async global->LDS, 16 bytes per lane; LDS dest = wave-uniform base + lane*16
__device__ __forceinline__ void gl_lds16(const void* g, void* l) {
  __builtin_amdgcn_global_load_lds(
      (const __attribute__((address_space(1))) void*)g,
      (__attribute__((address_space(3))) void*)l, 16, 0, 0);
}

// ---- fast fp64 transcendentals (rel err ~1e-11, way below f32 ulp) --------
__device__ __forceinline__ double rcp1p(double q) {  // 1/(1+q), q >= 0
  const double d = 1.0 + q;
  double r = (double)__builtin_amdgcn_rcpf((float)d);
  r = r * fma(-d, r, 2.0);
  r = r * fma(-d, r, 2.0);
  return r;
}
__device__ __forceinline__ double exp2d(double t) {  // 2^t, |t| < ~120
  const double n = rint(t);
  const double f = t - n;  // |f| <= 0.5
  double p = 1.0178086009239699e-07;   // ln2^9/9!
  p = fma(p, f, 1.3215542443841225e-06);
  p = fma(p, f, 1.5252733804059840e-05);
  p = fma(p, f, 1.5403530393381610e-04);
  p = fma(p, f, 1.3333558146428443e-03);
  p = fma(p, f, 9.6181291076284772e-03);
  p = fma(p, f, 5.5504108664821580e-02);
  p = fma(p, f, 2.4022650695910071e-01);
  p = fma(p, f, 6.9314718055994531e-01);
  p = fma(p, f, 1.0);
  const long long e = ((long long)(int)n + 1023) << 52;
  return p * __longlong_as_double(e);
}
__device__ __forceinline__ double sigd(double x) {   // 1/(1+e^-x)
  return rcp1p(exp2d(x * -1.4426950408889634));
}
__device__ __forceinline__ double tanhd(double x) {  // 2*sig(2x)-1
  return fma(2.0, rcp1p(exp2d(x * -2.8853900817779268)), -1.0);
}

// ---------------------------------------------------------------------------
// Fused fp16 split + fragment-order pack for one weight matrix [4H x K].
// chunk[(ut*nkt + kt)*512 + slot], slot = fm*64 + kg*16 + r15; element e:
//   W[gate*HID + ut*32 + ugrp*16 + r15][kt*32 + kg*8 + e],
//   gate = fm&3, ugrp = fm>>2   (GATE-INTERLEAVED: tile ni <-> gate).
// ---------------------------------------------------------------------------
__global__ __launch_bounds__(256) void pack_w(
    const float* __restrict__ src, int K, int nkt,
    uint4* __restrict__ dhi, uint4* __restrict__ dlo, int nchunks) {
  const int g = blockIdx.x * 256 + threadIdx.x;
  if (g >= nchunks) return;
  const int ut = g / (nkt * 512);
  const int rem = g - ut * (nkt * 512);
  const int kt = rem >> 9;
  const int slot = rem & 511;
  const int fm = slot >> 6, kg = (slot >> 4) & 3, r15 = slot & 15;
  const int row = (fm & 3) * HID + ut * 32 + (fm >> 2) * 16 + r15;
  const int col = kt * 32 + kg * 8;
  const float* s = src + (size_t)row * K + col;
  u16 hh[8], ll[8];
#pragma unroll
  for (int e = 0; e < 8; ++e) {
    const float x = s[e] * SCALE;
    const _Float16 h = (_Float16)x;
    const float rm = x - (float)h;
    const _Float16 l = (_Float16)rm;
    hh[e] = __builtin_bit_cast(u16, h);
    ll[e] = __builtin_bit_cast(u16, l);
  }
  dhi[g] = make_uint4((u32)hh[0] | ((u32)hh[1] << 16),
                      (u32)hh[2] | ((u32)hh[3] << 16),
                      (u32)hh[4] | ((u32)hh[5] << 16),
                      (u32)hh[6] | ((u32)hh[7] << 16));
  dlo[g] = make_uint4((u32)ll[0] | ((u32)ll[1] << 16),
                      (u32)ll[2] | ((u32)ll[3] << 16),
                      (u32)ll[4] | ((u32)ll[5] << 16),
                      (u32)ll[6] | ((u32)ll[7] << 16));
}

// ---------------------------------------------------------------------------
__global__ __launch_bounds__(256) void split_kernel(
    const float* __restrict__ src, u16* __restrict__ hi, u16* __restrict__ lo,
    int n) {
  const int i = blockIdx.x * 256 + threadIdx.x;
  if (i >= n) return;
  const float x = src[i] * SCALE;
  const _Float16 h = (_Float16)x;
  const float rem = x - (float)h;
  const _Float16 l = (_Float16)rem;
  hi[i] = __builtin_bit_cast(u16, h);
  lo[i] = __builtin_bit_cast(u16, l);
}

// ---------------------------------------------------------------------------
__global__ __launch_bounds__(256) void init_kernel(
    const int* __restrict__ prevs, float* __restrict__ c0,
    float* __restrict__ c1, u16* __restrict__ h0hi0, u16* __restrict__ h0lo0,
    u16* __restrict__ h0hi1, u16* __restrict__ h0lo1,
    u16* __restrict__ h1hi0, u16* __restrict__ h1lo0,
    u16* __restrict__ h1hi1, u16* __restrict__ h1lo1,
    int* __restrict__ prev, int* __restrict__ is_end,
    int* __restrict__ lengths, u32* __restrict__ keys,
    int* __restrict__ out_tok) {
  const int tid = blockIdx.x * 256 + threadIdx.x;
  const int total = BATCH * HID;
  if (tid < total) {
    c0[tid] = 0.0f; c1[tid] = 0.0f;
    h0hi0[tid] = 0; h0lo0[tid] = 0; h0hi1[tid] = 0; h0lo1[tid] = 0;
    h1hi0[tid] = 0; h1lo0[tid] = 0; h1hi1[tid] = 0; h1lo1[tid] = 0;
  }
  if (tid < BATCH) {
    const int p = prevs[tid];
    prev[tid] = p;
    is_end[tid] = (p == EOS_TOK) ? 1 : 0;
    lengths[tid] = 0;
    out_tok[(size_t)tid * (MAXLEN + 1)] = p;
  }
  if (tid < MAXLEN) {
    u32 y0, y1;
    threefry2x32(0u, 42u, 0u, (u32)tid, y0, y1);
    keys[2 * tid] = y0;
    keys[2 * tid + 1] = y1;
  }
}

// ---------------------------------------------------------------------------
// MFMA LSTM layer. 256 blocks (8 mt x 32 ut), 512 threads = 8 waves (4wm x
// 2wn), each wave 64x64 output. gates = A0*W0^T + A1*W1^T (fp16x3), fused
// fast-fp64 in-register cell update (gate-interleaved acc).
// Staging: global_load_lds into a 3-deep LDS ring (3 x 48KB); per k-tile
// each wave issues exactly 6 loads (A:4, W:2). The loop waits with COUNTED
// vmcnt (12 = 2 tiles in flight) + raw s_barrier -- no vmcnt(0) drain.
// ---------------------------------------------------------------------------
template <bool GATHER, bool WRITE_F32>
__global__ __launch_bounds__(512) void lstm_mfma(
    const uint4* __restrict__ A0p_hi, const uint4* __restrict__ A0p_lo,
    const u16* __restrict__ Ehi, const u16* __restrict__ Elo,
    const int* __restrict__ ptok, int nk0,
    const uint4* __restrict__ A1p_hi, const uint4* __restrict__ A1p_lo,
    const uint4* __restrict__ W0hi, const uint4* __restrict__ W0lo,
    const uint4* __restrict__ W1hi, const uint4* __restrict__ W1lo,
    const float* __restrict__ bih, const float* __restrict__ bhh,
    float* __restrict__ Cst, float* __restrict__ Hf32,
    uint4* __restrict__ Hp_hi, uint4* __restrict__ Hp_lo) {
  __shared__ uint4 lds4[9216];  // 147456 B: 3 x 48KB ring buffers
  char* lds = (char*)lds4;

  const int tid = threadIdx.x;          // 0..511
  const int lane = tid & 63;
  const int wid = tid >> 6;             // 0..7
  const int wm = wid >> 1, wn = wid & 1;

  const int bid = blockIdx.x;           // 256 blocks
  const int swz = (bid & 7) * 32 + (bid >> 3);
  const int ut = swz >> 3;              // 0..31
  const int mt = swz & 7;               // 0..7
  const int u0 = ut * 32;
  const int row0 = mt * 256;

  const int r15 = lane & 15;
  const int kgrp = lane >> 4;           // 0..3
  int tok[2];
  if (GATHER) {
#pragma unroll
    for (int j = 0; j < 2; ++j)
      tok[j] = ptok[row0 + (j * 8 + wid) * 16 + r15];
  }

  const int NT = nk0 + NKT_H;           // 34 (layer0) or 64 (layer1)

  // ring buf stride 49152; A planes @0/16384 (1024 slots), W @32768/40960
  auto ldsA = [&](int buf, int pl, int slot) -> char* {
    return lds + buf * 49152 + pl * 16384 + slot * 16;
  };
  auto ldsW = [&](int buf, int pl, int slot) -> char* {
    return lds + buf * 49152 + 32768 + pl * 8192 + slot * 16;
  };

  // exactly 6 gl_lds16 per wave per stage (W:2, A:4) -- vmcnt counting
  auto stage = [&](int buf, int kt) {
    const bool s0 = kt < nk0;
    const int ktl = s0 ? kt : kt - nk0;
    const uint4* wh = s0 ? W0hi : W1hi;
    const uint4* wl = s0 ? W0lo : W1lo;
    const int wbase = (ut * (s0 ? nk0 : NKT_H) + ktl) * 512;
    {
      const int sb = wid * 64;
      gl_lds16(wh + wbase + sb + lane, ldsW(buf, 0, sb));
      gl_lds16(wl + wbase + sb + lane, ldsW(buf, 1, sb));
    }
    if (GATHER && s0) {
#pragma unroll
      for (int j = 0; j < 2; ++j) {
        const int sb = j * 512 + wid * 64;
        const size_t ao = (size_t)tok[j] * EMB + ktl * 32 + kgrp * 8;
        gl_lds16(Ehi + ao, ldsA(buf, 0, sb));
        gl_lds16(Elo + ao, ldsA(buf, 1, sb));
      }
    } else {
      const uint4* ah_ = s0 ? A0p_hi : A1p_hi;
      const uint4* al_ = s0 ? A0p_lo : A1p_lo;
      const int abase = (mt * NKT_H + ktl) * 1024;
#pragma unroll
      for (int j = 0; j < 2; ++j) {
        const int sb = j * 512 + wid * 64;
        gl_lds16(ah_ + abase + sb + lane, ldsA(buf, 0, sb));
        gl_lds16(al_ + abase + sb + lane, ldsA(buf, 1, sb));
      }
    }
  };

  f32x4 acc[4][4] = {};  // acc[mi][gate]

  auto compute = [&](int buf) {
    half8 ah[4], al[4];
#pragma unroll
    for (int mi = 0; mi < 4; ++mi) {
      ah[mi] = *(const half8*)ldsA(buf, 0, (wm * 4 + mi) * 64 + lane);
      al[mi] = *(const half8*)ldsA(buf, 1, (wm * 4 + mi) * 64 + lane);
    }
#pragma unroll
    for (int ni = 0; ni < 4; ++ni) {
      const half8 bh = *(const half8*)ldsW(buf, 0, (wn * 4 + ni) * 64 + lane);
      const half8 bl = *(const half8*)ldsW(buf, 1, (wn * 4 + ni) * 64 + lane);
#pragma unroll
      for (int mi = 0; mi < 4; ++mi) {
        acc[mi][ni] =
            __builtin_amdgcn_mfma_f32_16x16x32_f16(ah[mi], bh, acc[mi][ni], 0, 0, 0);
        acc[mi][ni] =
            __builtin_amdgcn_mfma_f32_16x16x32_f16(ah[mi], bl, acc[mi][ni], 0, 0, 0);
        acc[mi][ni] =
            __builtin_amdgcn_mfma_f32_16x16x32_f16(al[mi], bh, acc[mi][ni], 0, 0, 0);
      }
    }
  };

  // prologue: fill the 3-deep ring (18 loads/wave in flight)
  stage(0, 0);
  stage(1, 1);
  stage(2, 2);
  int b = 0;
#pragma unroll 1
  for (int t = 0; t < NT - 2; ++t) {
    // wait for oldest tile's 6 loads (2 tiles = 12 stay in flight)
    asm volatile("s_waitcnt vmcnt(12)" ::: "memory");
    __builtin_amdgcn_sched_barrier(0);
    __builtin_amdgcn_s_barrier();      // all waves' slice of tile t landed
    compute(b);
    __builtin_amdgcn_s_barrier();      // all waves done reading buf b
    if (t + 3 < NT) stage(b, t + 3);   // refill; stays in flight across iters
    b = (b == 2) ? 0 : b + 1;
  }
  // tail: t = NT-2 (one tile still in flight behind it)
  asm volatile("s_waitcnt vmcnt(6)" ::: "memory");
  __builtin_amdgcn_sched_barrier(0);
  __builtin_amdgcn_s_barrier();
  compute(b);
  __builtin_amdgcn_s_barrier();
  b = (b == 2) ? 0 : b + 1;
  // tail: t = NT-1 (last tile)
  asm volatile("s_waitcnt vmcnt(0)" ::: "memory");
  __builtin_amdgcn_sched_barrier(0);
  __builtin_amdgcn_s_barrier();
  compute(b);
  __syncthreads();  // full drain; epilogue overlays the ring buffers

  // ---- epilogue: in-register fast-fp64 cell update -------------------------
  const int u_loc = wn * 16 + r15;      // 0..31
  const int u = u0 + u_loc;
  double bsum[4];
#pragma unroll
  for (int g = 0; g < 4; ++g)
    bsum[g] = (double)bih[g * HID + u] + (double)bhh[g * HID + u];

  float* Cb = Cst + (size_t)(mt * 32 + ut) * 8192;  // [256 rows][32 units]
  u16* hhT = (u16*)lds;                 // [256][40] u16 (20KB)
  u16* hlT = (u16*)(lds + 20480);       // [256][40] u16
  const int hi4 = lane >> 4;

#pragma unroll
  for (int mi = 0; mi < 4; ++mi) {
#pragma unroll
    for (int r = 0; r < 4; ++r) {
      const int row = wm * 64 + mi * 16 + hi4 * 4 + r;
      const double gI = (double)acc[mi][0][r] * INV_S2 + bsum[0];
      const double gF = (double)acc[mi][1][r] * INV_S2 + bsum[1];
      const double gG = (double)acc[mi][2][r] * INV_S2 + bsum[2];
      const double gO = (double)acc[mi][3][r] * INV_S2 + bsum[3];
      const double ii = sigd(gI);
      const double ff = sigd(gF);
      const double gt = tanhd(gG);
      const double oo = sigd(gO);
      const int co = row * 32 + u_loc;
      const double cn = ff * (double)Cb[co] + ii * gt;
      Cb[co] = (float)cn;
      const float hf = (float)(oo * tanhd(cn));
      if (WRITE_F32) Hf32[(size_t)(row0 + row) * HID + u] = hf;
      const float hs = hf * SCALE;
      const _Float16 hh = (_Float16)hs;
      const float rm = hs - (float)hh;
      const _Float16 hl = (_Float16)rm;
      hhT[row * 40 + u_loc] = __builtin_bit_cast(u16, hh);
      hlT[row * 40 + u_loc] = __builtin_bit_cast(u16, hl);
    }
  }
  __syncthreads();

  // pack h hi/lo planes: 1024 chunks, 2 per thread, coalesced global stores
  const size_t mtut = ((size_t)mt * NKT_H + ut) * 1024;
#pragma unroll
  for (int j = 0; j < 2; ++j) {
    const int g = tid + j * 512;
    const int fA = g >> 6, kg = (g >> 4) & 3, rr = g & 15;
    const int row = fA * 16 + rr;
    const uint4 vh = *(const uint4*)(hhT + row * 40 + kg * 8);
    const uint4 vl = *(const uint4*)(hlT + row * 40 + kg * 8);
    Hp_hi[mtut + g] = vh;
    Hp_lo[mtut + g] = vl;
  }
}

// ---------------------------------------------------------------------------
// Logits + gumbel + argmax + EOS bookkeeping (fp64, proven exact).
// ---------------------------------------------------------------------------
__global__ __launch_bounds__(256) void sample_kernel(
    const float* __restrict__ h1, const float* __restrict__ Wout,
    const float* __restrict__ bout, const u32* __restrict__ keys, int t,
    int* __restrict__ prev, int* __restrict__ is_end, int* __restrict__ lengths,
    int* __restrict__ out_tok, int* __restrict__ len_out) {
  const int wave = threadIdx.x >> 6;
  const int lane = threadIdx.x & 63;
  const int row = blockIdx.x * 4 + wave;
  const int v = lane & 31;
  const int half = lane >> 5;

  const float* hseg = h1 + (size_t)row * HID + half * (HID / 2);
  const float* wseg = Wout + (size_t)v * HID + half * (HID / 2);

  double acc = 0.0;
#pragma unroll 4
  for (int k = 0; k < HID / 2; k += 4) {
    const float4 w = *(const float4*)(wseg + k);
    const float4 h = *(const float4*)(hseg + k);
    acc = fma((double)w.x, (double)h.x, acc);
    acc = fma((double)w.y, (double)h.y, acc);
    acc = fma((double)w.z, (double)h.z, acc);
    acc = fma((double)w.w, (double)h.w, acc);
  }
  acc += __shfl_xor(acc, 32);

  const u32 k0 = keys[2 * t], k1 = keys[2 * t + 1];
  u32 y0, y1;
  threefry2x32(k0, k1, 0u, (u32)(row * VOCAB + v), y0, y1);
  const u32 bits = y0 ^ y1;
  const float f = __uint_as_float((bits >> 9) | 0x3f800000u) - 1.0f;
  const float uu = fmaxf(f, 1.17549435e-38f);
  const double g = -log(-log((double)uu));

  double z = acc + (double)bout[v] + g;
  int idx = v;
#pragma unroll
  for (int m = 1; m < 32; m <<= 1) {
    const double zo = __shfl_xor(z, m);
    const int io = __shfl_xor(idx, m);
    if (zo > z || (zo == z && io < idx)) { z = zo; idx = io; }
  }

  if (lane == 0) {
    const int e = is_end[row];
    const int cur = e ? PAD_TOK : idx;
    const int len = lengths[row] + (e ? 0 : 1);
    const int enew = e | (cur == EOS_TOK ? 1 : 0);
    prev[row] = cur;
    is_end[row] = enew;
    lengths[row] = len;
    out_tok[(size_t)row * (MAXLEN + 1) + t + 1] = cur;
    if (len_out) len_out[row] = len + 1;  // reference returns lengths+1 (BOS)
  }
}

// ---------------------------------------------------------------------------
extern "C" void kernel_launch(void* const* d_in, const int* in_sizes, int n_in,
                              void* d_out, int out_size, void* d_ws,
                              size_t ws_size, hipStream_t stream) {
  const int* prevs = (const int*)d_in[0];
  const float* emb = (const float*)d_in[1];
  const float* Wih0 = (const float*)d_in[2];
  const float* Whh0 = (const float*)d_in[3];
  const float* bih0 = (const float*)d_in[4];
  const float* bhh0 = (const float*)d_in[5];
  const float* Wih1 = (const float*)d_in[6];
  const float* Whh1 = (const float*)d_in[7];
  const float* bih1 = (const float*)d_in[8];
  const float* bhh1 = (const float*)d_in[9];
  const float* Wout = (const float*)d_in[10];
  const float* bout = (const float*)d_in[11];

  const size_t SH = (size_t)BATCH * HID;       // 2M elements
  const size_t CH = SH / 8;                    // 262144 uint4 per h plane
  const size_t CW = (size_t)32 * NKT_H * 512;  // 524288 chunks (K=1024)
  const size_t CW0 = (size_t)32 * 2 * 512;     // 32768 chunks (Wih0, K=64)

  float* c0 = (float*)d_ws;                    // block layout [mt*32+ut][256][32]
  float* c1 = c0 + SH;
  float* h1f = c1 + SH;
  uint4* q = (uint4*)(h1f + SH);
  uint4* ph0hi[2] = {q, q + CH};
  uint4* ph0lo[2] = {q + 2 * CH, q + 3 * CH};
  uint4* ph1hi[2] = {q + 4 * CH, q + 5 * CH};
  uint4* ph1lo[2] = {q + 6 * CH, q + 7 * CH};
  uint4* pw = q + 8 * CH;
  uint4* pwih0h = pw;              uint4* pwih0l = pwih0h + CW0;
  uint4* pwhh0h = pwih0l + CW0;    uint4* pwhh0l = pwhh0h + CW;
  uint4* pwih1h = pwhh0l + CW;     uint4* pwih1l = pwih1h + CW;
  uint4* pwhh1h = pwih1l + CW;     uint4* pwhh1l = pwhh1h + CW;
  u16* embh = (u16*)(pwhh1l + CW);
  u16* embl = embh + VOCAB * EMB;
  int* prev = (int*)(embl + VOCAB * EMB);
  int* is_end = prev + BATCH;
  int* lengths = is_end + BATCH;
  u32* keys = (u32*)(lengths + BATCH);
  // total ~105 MB

  int* out_tok = (int*)d_out;
  int* len_out = out_tok + (size_t)BATCH * (MAXLEN + 1);

  init_kernel<<<dim3((BATCH * HID) / 256), 256, 0, stream>>>(
      prevs, c0, c1, (u16*)ph0hi[0], (u16*)ph0lo[0], (u16*)ph0hi[1],
      (u16*)ph0lo[1], (u16*)ph1hi[0], (u16*)ph1lo[0], (u16*)ph1hi[1],
      (u16*)ph1lo[1], prev, is_end, lengths, keys, out_tok);

  split_kernel<<<dim3((VOCAB * EMB + 255) / 256), 256, 0, stream>>>(
      emb, embh, embl, VOCAB * EMB);
  pack_w<<<dim3((int)((CW0 + 255) / 256)), 256, 0, stream>>>(
      Wih0, EMB, 2, pwih0h, pwih0l, (int)CW0);
  pack_w<<<dim3((int)((CW + 255) / 256)), 256, 0, stream>>>(
      Whh0, HID, NKT_H, pwhh0h, pwhh0l, (int)CW);
  pack_w<<<dim3((int)((CW + 255) / 256)), 256, 0, stream>>>(
      Wih1, HID, NKT_H, pwih1h, pwih1l, (int)CW);
  pack_w<<<dim3((int)((CW + 255) / 256)), 256, 0, stream>>>(
      Whh1, HID, NKT_H, pwhh1h, pwhh1l, (int)CW);

  int p = 0;
  for (int t = 0; t < MAXLEN; ++t) {
    lstm_mfma<true, false><<<dim3(256), 512, 0, stream>>>(
        nullptr, nullptr, embh, embl, prev, 2, ph0hi[p], ph0lo[p],
        pwih0h, pwih0l, pwhh0h, pwhh0l, bih0, bhh0, c0, nullptr,
        ph0hi[p ^ 1], ph0lo[p ^ 1]);
    lstm_mfma<false, true><<<dim3(256), 512, 0, stream>>>(
        ph0hi[p ^ 1], ph0lo[p ^ 1], nullptr, nullptr, nullptr, NKT_H,
        ph1hi[p], ph1lo[p], pwih1h, pwih1l, pwhh1h, pwhh1l, bih1, bhh1,
        c1, h1f, ph1hi[p ^ 1], ph1lo[p ^ 1]);
    sample_kernel<<<dim3(BATCH / 4), 256, 0, stream>>>(
        h1f, Wout, bout, keys, t, prev, is_end, lengths, out_tok,
        (t == MAXLEN - 1) ? len_out : nullptr);
    p ^= 1;
  }
  (void)in_sizes; (void)n_in; (void)out_size; (void)ws_size;
}